// Round 16
// baseline (208.475 us; speedup 1.0000x reference)
//
#include <hip/hip_runtime.h>

#define S_LEN 2048
#define NHQ 8
#define NKV 2
#define HD 256
#define KVB 32

typedef __attribute__((ext_vector_type(8))) short bf16x8;
typedef __attribute__((ext_vector_type(4))) short bf16x4;
typedef __attribute__((ext_vector_type(4))) float f32x4;
typedef __attribute__((ext_vector_type(16))) float f32x16;
typedef __attribute__((ext_vector_type(4))) unsigned u32x4;

__device__ __forceinline__ short f2bf(float f) {
    unsigned u = __builtin_bit_cast(unsigned, f);
    u += 0x7FFFu + ((u >> 16) & 1u);
    return (short)(u >> 16);
}
__device__ __forceinline__ float bf2f(short s) {
    unsigned u = ((unsigned)(unsigned short)s) << 16;
    return __builtin_bit_cast(float, u);
}
__device__ __forceinline__ unsigned cvtpk(float a, float b) {
    unsigned r;
    asm("v_cvt_pk_bf16_f32 %0, %1, %2" : "=v"(r) : "v"(a), "v"(b));
    return r;
}
__device__ __forceinline__ void gload16(const short* g, short* l) {
    __builtin_amdgcn_global_load_lds((const __attribute__((address_space(1))) unsigned*)g,
                                     (__attribute__((address_space(3))) unsigned*)l, 16, 0, 0);
}
__device__ __forceinline__ float bperm(int srclane, float v) {
    return __builtin_bit_cast(float,
        __builtin_amdgcn_ds_bpermute(srclane * 4, __builtin_bit_cast(int, v)));
}

// ---------------- fp32 -> bf16 convert ----------------
__global__ __launch_bounds__(256) void cvt_kernel(const float* __restrict__ in,
                                                  short* __restrict__ out, int n) {
    int i = (blockIdx.x * 256 + threadIdx.x) * 4;
    if (i + 3 < n) {
        float4 f = *(const float4*)(in + i);
        bf16x4 o;
        o[0] = f2bf(f.x); o[1] = f2bf(f.y); o[2] = f2bf(f.z); o[3] = f2bf(f.w);
        *(bf16x4*)(out + i) = o;
    }
}

// ------- fused weight prep: all four W[K][N] -> bf16 Wt[N][K] transposes ----
__global__ __launch_bounds__(256) void wt_all_kernel(const float* __restrict__ wq,
                                                     const float* __restrict__ wk,
                                                     const float* __restrict__ wv,
                                                     const float* __restrict__ wo,
                                                     short* __restrict__ wfus,
                                                     short* __restrict__ wot) {
    __shared__ short tile[64][72];
    int bid = blockIdx.x;
    const float* in; short* out; int K, N, nx, base;
    if (bid < 256)      { in = wq; out = wfus;             K = 512;  N = 2048; nx = 32; base = 0;   }
    else if (bid < 320) { in = wk; out = wfus + 2048 * 512; K = 512;  N = 512;  nx = 8;  base = 256; }
    else if (bid < 384) { in = wv; out = wfus + 2560 * 512; K = 512;  N = 512;  nx = 8;  base = 320; }
    else                { in = wo; out = wot;              K = 2048; N = 512;  nx = 8;  base = 384; }
    int lb = bid - base;
    int n0 = (lb % nx) * 64, k0 = (lb / nx) * 64;
    int t = threadIdx.x;
    #pragma unroll
    for (int i = 0; i < 16; i++) {
        int flat = i * 256 + t; int r = flat >> 6, c = flat & 63;
        tile[r][c] = f2bf(in[(long)(k0 + r) * N + n0 + c]);
    }
    __syncthreads();
    #pragma unroll
    for (int i = 0; i < 16; i++) {
        int flat = i * 256 + t; int r = flat >> 6, c = flat & 63;
        out[(long)(n0 + r) * K + k0 + c] = tile[c][r];
    }
}

// ---------------- m97-style GEMM: C[M][N] = A[M][K] @ Bt[N][K]^T ------------
template<int BN, int WRITE_BF16>
__global__ __launch_bounds__(256) void gemm_bt(const short* __restrict__ A,
                                               const short* __restrict__ Bt,
                                               void* __restrict__ Cv,
                                               int M, int N, int K) {
    constexpr int NI = BN / 32;          // B-frags per wave
    __shared__ short As[128 * 32];
    __shared__ short Bs[BN * 32];
    const int t = threadIdx.x;
    const int lane = t & 63, w = t >> 6;
    const int lr = lane & 15, lg = lane >> 4;
    const int m0 = blockIdx.y * 128, n0 = blockIdx.x * BN;
    const int wm = (w >> 1) * 64, wn = (w & 1) * (BN / 2);

    f32x4 acc[4][NI];
    #pragma unroll
    for (int i = 0; i < 4; i++)
        #pragma unroll
        for (int j = 0; j < NI; j++) acc[i][j] = (f32x4){0.f, 0.f, 0.f, 0.f};

    for (int k0 = 0; k0 < K; k0 += 32) {
        __syncthreads();
        #pragma unroll
        for (int r = 0; r < 2; r++) {            // A tile: 128x32 = 8 KB
            int sbase = r * 2048 + w * 512;
            int srow = (sbase + lane * 8) >> 5, scol = (sbase + lane * 8) & 31;
            gload16(A + (long)(m0 + srow) * K + k0 + scol, &As[sbase]);
        }
        #pragma unroll
        for (int r = 0; r < BN / 64; r++) {      // B tile: BNx32
            int sbase = r * 2048 + w * 512;
            int srow = (sbase + lane * 8) >> 5, scol = (sbase + lane * 8) & 31;
            gload16(Bt + (long)(n0 + srow) * K + k0 + scol, &Bs[sbase]);
        }
        __syncthreads();
        bf16x8 af[4], bfr[NI];
        #pragma unroll
        for (int mi = 0; mi < 4; mi++)
            af[mi] = *(const bf16x8*)&As[(wm + mi * 16 + lr) * 32 + lg * 8];
        #pragma unroll
        for (int ni = 0; ni < NI; ni++)
            bfr[ni] = *(const bf16x8*)&Bs[(wn + ni * 16 + lr) * 32 + lg * 8];
        #pragma unroll
        for (int mi = 0; mi < 4; mi++)
            #pragma unroll
            for (int ni = 0; ni < NI; ni++)
                acc[mi][ni] = __builtin_amdgcn_mfma_f32_16x16x32_bf16(af[mi], bfr[ni], acc[mi][ni], 0, 0, 0);
    }
    #pragma unroll
    for (int mi = 0; mi < 4; mi++)
    #pragma unroll
    for (int ni = 0; ni < NI; ni++)
    #pragma unroll
    for (int r = 0; r < 4; r++) {
        long row = m0 + wm + mi * 16 + lg * 4 + r;
        long col = n0 + wn + ni * 16 + lr;
        float v = acc[mi][ni][r];
        if (WRITE_BF16) ((short*)Cv)[row * N + col] = f2bf(v);
        else            ((float*)Cv)[row * N + col] = v;
    }
}

// ------- fused RMSNorm + partial RoPE for Q and K in one launch -------------
__global__ __launch_bounds__(256) void norm_rope2_kernel(
    const short* __restrict__ C, short* __restrict__ qout, short* __restrict__ kout,
    const float* __restrict__ qw, const float* __restrict__ kw,
    const float* __restrict__ cosb, const float* __restrict__ sinb) {
    int bid = blockIdx.x;
    bool isQ = bid < 8192;
    int H        = isQ ? 8 : 2;
    long cofs    = isQ ? 0L : 2048L;
    const float* w = isQ ? qw : kw;
    short* out   = isQ ? qout : kout;
    long ob      = isQ ? 4194304L : 1048576L;
    long oh      = isQ ? 256L : 524288L;
    long os      = isQ ? 2048L : 256L;
    float scale  = isQ ? 0.0625f : 1.0f;
    int vec = (isQ ? bid : bid - 8192) * 4 + (threadIdx.x >> 6);
    int lane = threadIdx.x & 63;
    int token = vec / H, head = vec % H;
    int b = token / S_LEN, s = token % S_LEN;

    bf16x4 xv = *(const bf16x4*)(C + (long)token * 3072 + cofs + head * 256 + lane * 4);
    float x0 = bf2f(xv[0]), x1 = bf2f(xv[1]), x2 = bf2f(xv[2]), x3 = bf2f(xv[3]);
    float ss = x0 * x0 + x1 * x1 + x2 * x2 + x3 * x3;
    #pragma unroll
    for (int m = 1; m < 64; m <<= 1) ss += __shfl_xor(ss, m);
    float inv = rsqrtf(ss * (1.f / 256.f) + 1e-6f);

    float4 wv = *(const float4*)(w + lane * 4);
    float y0 = x0 * inv * (1.f + wv.x);
    float y1 = x1 * inv * (1.f + wv.y);
    float y2 = x2 * inv * (1.f + wv.z);
    float y3 = x3 * inv * (1.f + wv.w);

    if (lane < 16) {
        float2 c = *(const float2*)&cosb[s * 32 + lane * 2];
        float2 sn = *(const float2*)&sinb[s * 32 + lane * 2];
        float a0 = y0 * c.x - y1 * sn.x, b0 = y0 * sn.x + y1 * c.x;
        float a1 = y2 * c.y - y3 * sn.y, b1 = y2 * sn.y + y3 * c.y;
        y0 = a0; y1 = b0; y2 = a1; y3 = b1;
    }
    y0 *= scale; y1 *= scale; y2 *= scale; y3 *= scale;
    long oidx = (long)b * ob + (long)head * oh + (long)s * os + lane * 4;
    bf16x4 o; o[0] = f2bf(y0); o[1] = f2bf(y1); o[2] = f2bf(y2); o[3] = f2bf(y3);
    *(bf16x4*)(out + oidx) = o;
}

// ---------------- V transpose: C[token][2560+kv*256+d] -> vr[b][kv][d][s] ---
__global__ __launch_bounds__(256) void transpose_v_kernel(const short* __restrict__ C,
                                                          short* __restrict__ vr) {
    __shared__ short tile[64][65];
    int s0 = blockIdx.x * 64, d0 = blockIdx.y * 64;
    int bkv = blockIdx.z; int b = bkv >> 1, kv = bkv & 1;
    int t = threadIdx.x;
    #pragma unroll
    for (int i = 0; i < 16; i++) {
        int flat = i * 256 + t; int si = flat >> 6, di = flat & 63;
        tile[si][di] = C[(long)(b * S_LEN + s0 + si) * 3072 + 2560 + kv * 256 + d0 + di];
    }
    __syncthreads();
    #pragma unroll
    for (int i = 0; i < 16; i++) {
        int flat = i * 256 + t; int di = flat >> 6, si = flat & 63;
        vr[(long)(bkv * 256 + d0 + di) * S_LEN + s0 + si] = tile[si][di];
    }
}

// ---------------- flash attention: GQA-shared K/V, 8 waves, dbuf ring -------
// Block = 32 q-rows x ALL 4 heads of one (b,kv). 8 waves = 4 heads x 2 key
// parities. Grid = 256 (1 block/CU, bkv = idx&3 -> 2MB K/V per XCD L2).
// Phase = 64 keys; 2x64KB LDS ring; vmcnt(8) gives 2-phase load distance.
// Q-prep BEFORE loop, merge AFTER (no in-loop resets -> no acc spill).
__global__ __launch_bounds__(512, 1) void flash_kernel(const short* __restrict__ Q,
                                                       const short* __restrict__ Kt,
                                                       const short* __restrict__ Vt,
                                                       short* __restrict__ O) {
    // buf i at i*65536: K 64x512B (swz (key&7)<<4) + V 256x128B (swz (d&7)<<4)
    // epilogue: accb 128KB + ml 1KB reuse the ring. Total 132096.
    __shared__ __align__(16) char smem[132096];

    int idx = blockIdx.x;
    int chunk = idx >> 2;                    // 0..63: q rows [32c, 32c+32)
    int bkv = idx & 3;                       // XCD (idx&7) serves one bkv
    int b = bkv >> 1, kv = bkv & 1;
    int t = threadIdx.x, lane = t & 63, w = t >> 6;
    int hh = w >> 1, p = w & 1;              // head-in-group, key parity
    int h = kv * 4 + hh;
    int ln = lane & 31, hi = lane >> 5;
    int q0 = chunk * 32;
    int qg = q0 + ln;                        // this lane's q row (score column)

    const short* Kb = Kt + (long)(b * NKV + kv) * S_LEN * HD;
    const short* Vb = Vt + (long)(b * NKV + kv) * HD * S_LEN;

    const int nph = (chunk >> 1) + 1;        // phases of 64 keys

    // stage 64-key K/V tile at key base 64*f into buf (8 loads/thread)
    auto stage = [&](int buf, int f) {
        int k0s = f * 64;
        char* base = smem + buf * 65536;
        #pragma unroll
        for (int cc = 0; cc < 4; cc++) {
            int o = cc * 8192 + w * 1024 + lane * 16;     // byte offset in tile
            int key = o >> 9, db = o & 511;
            gload16(Kb + (long)(k0s + key) * HD + ((db ^ ((key & 7) << 4)) >> 1),
                    (short*)(base + cc * 8192 + w * 1024));
            int d = o >> 7, kb = o & 127;
            gload16(Vb + (long)d * S_LEN + k0s + ((kb ^ ((d & 7) << 4)) >> 1),
                    (short*)(base + 32768 + cc * 8192 + w * 1024));
        }
    };

    stage(0, 0);
    if (nph > 1) stage(1, 1);

    // Q fragments in registers: Q[q=ln][dc*16 + hi*8 + e] (pre-normed/roped)
    bf16x8 qf[16];
    {
        const short* qrow = Q + ((long)(b * S_LEN + qg) * NHQ + h) * HD + hi * 8;
        #pragma unroll
        for (int dc = 0; dc < 16; dc++) qf[dc] = *(const bf16x8*)&qrow[dc * 16];
    }

    f32x16 acc[8];
    #pragma unroll
    for (int i = 0; i < 8; i++)
        #pragma unroll
        for (int r = 0; r < 16; r++) acc[i][r] = 0.f;
    float m = -1e30f, l = 0.f;

    auto compute = [&](int buf, int k0) {
        const char* Ks = (const char*)smem + buf * 65536 + p * 16384;
        const char* Vs = (const char*)smem + buf * 65536 + 32768;
        // ---- QK^T (swapped): s = K * Q, D[key][q]; 2 chains ----
        f32x16 sA, sB;
        #pragma unroll
        for (int r = 0; r < 16; r++) { sA[r] = 0.f; sB[r] = 0.f; }
        __builtin_amdgcn_s_setprio(1);
        #pragma unroll
        for (int dc = 0; dc < 16; dc += 2) {
            int kb0 = (dc * 32 + hi * 16) ^ ((ln & 7) << 4);
            int kb1 = ((dc + 1) * 32 + hi * 16) ^ ((ln & 7) << 4);
            bf16x8 kf0 = *(const bf16x8*)(Ks + ln * 512 + kb0);
            bf16x8 kf1 = *(const bf16x8*)(Ks + ln * 512 + kb1);
            sA = __builtin_amdgcn_mfma_f32_32x32x16_bf16(kf0, qf[dc],     sA, 0, 0, 0);
            sB = __builtin_amdgcn_mfma_f32_32x32x16_bf16(kf1, qf[dc + 1], sB, 0, 0, 0);
        }
        __builtin_amdgcn_s_setprio(0);
        f32x16 s;
        #pragma unroll
        for (int r = 0; r < 16; r++) s[r] = sA[r] + sB[r];

        // ---- mask + online softmax, fully in-register ----
        if (k0 + KVB - 1 > q0) {
            #pragma unroll
            for (int r = 0; r < 16; r++) {
                int key_g = k0 + (r & 3) + 8 * (r >> 2) + 4 * hi;
                if (key_g > qg) s[r] = -1e30f;
            }
        }
        float mt = s[0];
        #pragma unroll
        for (int r = 1; r < 16; r++) mt = fmaxf(mt, s[r]);
        mt = fmaxf(mt, __shfl_xor(mt, 32));
        float mn = m;
        if (!__all(mt <= m + 8.f)) {           // defer-max (T13)
            mn = fmaxf(m, mt);
            float f = __expf(m - mn);
            m = mn;
            float fr[16];
            #pragma unroll
            for (int r = 0; r < 16; r++)
                fr[r] = bperm((r & 3) + 8 * (r >> 2) + 4 * hi, f);
            #pragma unroll
            for (int i = 0; i < 8; i++)
                #pragma unroll
                for (int r = 0; r < 16; r++) acc[i][r] *= fr[r];
            l *= f;
        }
        float pr[16], ps = 0.f;
        #pragma unroll
        for (int r = 0; r < 16; r++) { pr[r] = __expf(s[r] - mn); ps += pr[r]; }
        ps += __shfl_xor(ps, 32);
        l += ps;

        // ---- P -> bf16 A-fragments via cvt_pk + permlane32_swap (T12) ----
        unsigned pw[8];
        #pragma unroll
        for (int kc = 0; kc < 2; kc++) {
            unsigned X = cvtpk(pr[kc * 8 + 0], pr[kc * 8 + 1]);
            unsigned Y = cvtpk(pr[kc * 8 + 4], pr[kc * 8 + 5]);
            unsigned Z = cvtpk(pr[kc * 8 + 2], pr[kc * 8 + 3]);
            unsigned W = cvtpk(pr[kc * 8 + 6], pr[kc * 8 + 7]);
            asm volatile("v_permlane32_swap_b32 %0, %1" : "+v"(X), "+v"(Y));
            asm volatile("v_permlane32_swap_b32 %0, %1" : "+v"(Z), "+v"(W));
            pw[kc * 4 + 0] = X; pw[kc * 4 + 1] = Z;
            pw[kc * 4 + 2] = Y; pw[kc * 4 + 3] = W;
        }
        u32x4 w0v = {pw[0], pw[1], pw[2], pw[3]};
        u32x4 w1v = {pw[4], pw[5], pw[6], pw[7]};
        bf16x8 pa0 = __builtin_bit_cast(bf16x8, w0v);
        bf16x8 pa1 = __builtin_bit_cast(bf16x8, w1v);

        // ---- PV over this wave's 32 keys (parity half of 128B V rows) ----
        __builtin_amdgcn_s_setprio(1);
        #pragma unroll
        for (int db = 0; db < 8; db++) {
            int drow = db * 32 + ln;
            int sw = (drow & 7) << 4;
            bf16x8 vf0 = *(const bf16x8*)(Vs + drow * 128 + ((p * 64 + hi * 16) ^ sw));
            bf16x8 vf1 = *(const bf16x8*)(Vs + drow * 128 + ((p * 64 + 32 + hi * 16) ^ sw));
            acc[db] = __builtin_amdgcn_mfma_f32_32x32x16_bf16(pa0, vf0, acc[db], 0, 0, 0);
            acc[db] = __builtin_amdgcn_mfma_f32_32x32x16_bf16(pa1, vf1, acc[db], 0, 0, 0);
        }
        __builtin_amdgcn_s_setprio(0);
    };

    for (int f = 0; f < nph; f++) {
        if (f + 1 < nph) { asm volatile("s_waitcnt vmcnt(8)" ::: "memory"); }
        else             { asm volatile("s_waitcnt vmcnt(0)" ::: "memory"); }
        __builtin_amdgcn_s_barrier();
        int k0 = f * 64 + 32 * p;
        if (k0 <= q0 + 31) compute(f & 1, k0);
        __builtin_amdgcn_s_barrier();
        if (f + 2 < nph) stage(f & 1, f + 2);
        __builtin_amdgcn_sched_barrier(0);
    }

    // ---- parity merge epilogue (ring LDS is dead) ----
    float* accb = (float*)smem;                 // [hh][128][64] f32 = 128 KB
    float* mlb  = (float*)(smem + 131072);      // m: [0,128), l: [128,256)
    if (p == 1) {
        #pragma unroll
        for (int db = 0; db < 8; db++)
            #pragma unroll
            for (int r = 0; r < 16; r++)
                accb[hh * 8192 + (db * 16 + r) * 64 + hi * 32 + ln] = acc[db][r];
        if (hi == 0) { mlb[hh * 32 + ln] = m; mlb[128 + hh * 32 + ln] = l; }
    }
    __syncthreads();
    if (p == 0) {
        float m1 = mlb[hh * 32 + ln], l1 = mlb[128 + hh * 32 + ln];
        float M  = fmaxf(m, m1);
        float f0 = __expf(m - M), f1 = __expf(m1 - M);
        float lt = l * f0 + l1 * f1;
        float w0 = f0 / lt, w1 = f1 / lt;
        float fr0[16], fr1[16];
        #pragma unroll
        for (int r = 0; r < 16; r++) {
            int crow = (r & 3) + 8 * (r >> 2) + 4 * hi;
            fr0[r] = bperm(crow, w0);
            fr1[r] = bperm(crow, w1);
        }
        #pragma unroll
        for (int db = 0; db < 8; db++)
            #pragma unroll
            for (int r = 0; r < 16; r++) {
                float a1 = accb[hh * 8192 + (db * 16 + r) * 64 + hi * 32 + ln];
                int qrow = q0 + (r & 3) + 8 * (r >> 2) + 4 * hi;
                O[(long)(b * S_LEN + qrow) * 2048 + h * HD + db * 32 + ln] =
                    f2bf(acc[db][r] * fr0[r] + a1 * fr1[r]);
            }
    }
}

extern "C" void kernel_launch(void* const* d_in, const int* in_sizes, int n_in,
                              void* d_out, int out_size, void* d_ws, size_t ws_size,
                              hipStream_t stream) {
    const float* x    = (const float*)d_in[0];
    const float* cosb = (const float*)d_in[1];
    const float* sinb = (const float*)d_in[2];
    // d_in[3] = mask: equivalent to causal; computed analytically in-kernel
    const float* wq   = (const float*)d_in[4];
    const float* wk   = (const float*)d_in[5];
    const float* wv   = (const float*)d_in[6];
    const float* wo   = (const float*)d_in[7];
    const float* qnw  = (const float*)d_in[8];
    const float* knw  = (const float*)d_in[9];
    float* out = (float*)d_out;

    char* ws = (char*)d_ws;
    short* xb   = (short*)(ws + 0);          // 4096x512 bf16               [0, 4194304)
    short* wfus = (short*)(ws + 4194304);    // [3072][512] wq|wk|wv^T      [4194304, 7340032)
    short* wot  = (short*)(ws + 7340032);    // [512][2048] wo^T            [7340032, 9437184)
    short* C    = (short*)(ws + 9437184);    // 4096x3072 fused QKV out     [9437184, 34603008)
    short* ao   = (short*)(ws + 9437184);    // flash out aliases C (C dead by then)
    short* qro  = (short*)(ws + 34603008);   // 4096x2048 roped Q           [34603008, 51380224)
    short* kr   = (short*)(ws + 51380224);   // [b][kv][s][d] 4 MB          [51380224, 55574528)
    short* vr   = (short*)(ws + 55574528);   // [b][kv][d][s] 4 MB          [55574528, 59768832)

    cvt_kernel<<<2048, 256, 0, stream>>>(x, xb, 2097152);
    wt_all_kernel<<<640, 256, 0, stream>>>(wq, wk, wv, wo, wfus, wot);

    // fused QKV projection: C[4096][3072]
    gemm_bt<128, 1><<<dim3(24, 32), 256, 0, stream>>>(xb, wfus, C, 4096, 3072, 512);

    // Q (scale 1/16 folded) + K norm/rope in one launch
    norm_rope2_kernel<<<10240, 256, 0, stream>>>(C, qro, kr, qnw, knw, cosb, sinb);
    transpose_v_kernel<<<dim3(32, 4, 4), 256, 0, stream>>>(C, vr);

    flash_kernel<<<256, 512, 0, stream>>>(qro, kr, vr, ao);

    gemm_bt<64, 0><<<dim3(8, 32), 256, 0, stream>>>(ao, wot, out, 4096, 512, 2048);
}

// Round 17
// 198.715 us; speedup vs baseline: 1.0491x; 1.0491x over previous
//
#include <hip/hip_runtime.h>

#define S_LEN 2048
#define NHQ 8
#define NKV 2
#define HD 256
#define KVB 32

typedef __attribute__((ext_vector_type(8))) short bf16x8;
typedef __attribute__((ext_vector_type(4))) short bf16x4;
typedef __attribute__((ext_vector_type(4))) float f32x4;
typedef __attribute__((ext_vector_type(16))) float f32x16;
typedef __attribute__((ext_vector_type(4))) unsigned u32x4;

__device__ __forceinline__ short f2bf(float f) {
    unsigned u = __builtin_bit_cast(unsigned, f);
    u += 0x7FFFu + ((u >> 16) & 1u);
    return (short)(u >> 16);
}
__device__ __forceinline__ float bf2f(short s) {
    unsigned u = ((unsigned)(unsigned short)s) << 16;
    return __builtin_bit_cast(float, u);
}
__device__ __forceinline__ unsigned cvtpk(float a, float b) {
    unsigned r;
    asm("v_cvt_pk_bf16_f32 %0, %1, %2" : "=v"(r) : "v"(a), "v"(b));
    return r;
}
__device__ __forceinline__ void gload16(const short* g, short* l) {
    __builtin_amdgcn_global_load_lds((const __attribute__((address_space(1))) unsigned*)g,
                                     (__attribute__((address_space(3))) unsigned*)l, 16, 0, 0);
}
__device__ __forceinline__ float bperm(int srclane, float v) {
    return __builtin_bit_cast(float,
        __builtin_amdgcn_ds_bpermute(srclane * 4, __builtin_bit_cast(int, v)));
}

// ---------------- fp32 -> bf16 convert ----------------
__global__ __launch_bounds__(256) void cvt_kernel(const float* __restrict__ in,
                                                  short* __restrict__ out, int n) {
    int i = (blockIdx.x * 256 + threadIdx.x) * 4;
    if (i + 3 < n) {
        float4 f = *(const float4*)(in + i);
        bf16x4 o;
        o[0] = f2bf(f.x); o[1] = f2bf(f.y); o[2] = f2bf(f.z); o[3] = f2bf(f.w);
        *(bf16x4*)(out + i) = o;
    }
}

// ------- fused weight prep: all four W[K][N] -> bf16 Wt[N][K] transposes ----
__global__ __launch_bounds__(256) void wt_all_kernel(const float* __restrict__ wq,
                                                     const float* __restrict__ wk,
                                                     const float* __restrict__ wv,
                                                     const float* __restrict__ wo,
                                                     short* __restrict__ wfus,
                                                     short* __restrict__ wot) {
    __shared__ short tile[64][72];
    int bid = blockIdx.x;
    const float* in; short* out; int K, N, nx, base;
    if (bid < 256)      { in = wq; out = wfus;             K = 512;  N = 2048; nx = 32; base = 0;   }
    else if (bid < 320) { in = wk; out = wfus + 2048 * 512; K = 512;  N = 512;  nx = 8;  base = 256; }
    else if (bid < 384) { in = wv; out = wfus + 2560 * 512; K = 512;  N = 512;  nx = 8;  base = 320; }
    else                { in = wo; out = wot;              K = 2048; N = 512;  nx = 8;  base = 384; }
    int lb = bid - base;
    int n0 = (lb % nx) * 64, k0 = (lb / nx) * 64;
    int t = threadIdx.x;
    #pragma unroll
    for (int i = 0; i < 16; i++) {
        int flat = i * 256 + t; int r = flat >> 6, c = flat & 63;
        tile[r][c] = f2bf(in[(long)(k0 + r) * N + n0 + c]);
    }
    __syncthreads();
    #pragma unroll
    for (int i = 0; i < 16; i++) {
        int flat = i * 256 + t; int r = flat >> 6, c = flat & 63;
        out[(long)(n0 + r) * K + k0 + c] = tile[c][r];
    }
}

// ---------------- m97-style GEMM: C[M][N] = A[M][K] @ Bt[N][K]^T ------------
template<int BN, int WRITE_BF16>
__global__ __launch_bounds__(256) void gemm_bt(const short* __restrict__ A,
                                               const short* __restrict__ Bt,
                                               void* __restrict__ Cv,
                                               int M, int N, int K) {
    constexpr int NI = BN / 32;          // B-frags per wave
    __shared__ short As[128 * 32];
    __shared__ short Bs[BN * 32];
    const int t = threadIdx.x;
    const int lane = t & 63, w = t >> 6;
    const int lr = lane & 15, lg = lane >> 4;
    const int m0 = blockIdx.y * 128, n0 = blockIdx.x * BN;
    const int wm = (w >> 1) * 64, wn = (w & 1) * (BN / 2);

    f32x4 acc[4][NI];
    #pragma unroll
    for (int i = 0; i < 4; i++)
        #pragma unroll
        for (int j = 0; j < NI; j++) acc[i][j] = (f32x4){0.f, 0.f, 0.f, 0.f};

    for (int k0 = 0; k0 < K; k0 += 32) {
        __syncthreads();
        #pragma unroll
        for (int r = 0; r < 2; r++) {            // A tile: 128x32 = 8 KB
            int sbase = r * 2048 + w * 512;
            int srow = (sbase + lane * 8) >> 5, scol = (sbase + lane * 8) & 31;
            gload16(A + (long)(m0 + srow) * K + k0 + scol, &As[sbase]);
        }
        #pragma unroll
        for (int r = 0; r < BN / 64; r++) {      // B tile: BNx32
            int sbase = r * 2048 + w * 512;
            int srow = (sbase + lane * 8) >> 5, scol = (sbase + lane * 8) & 31;
            gload16(Bt + (long)(n0 + srow) * K + k0 + scol, &Bs[sbase]);
        }
        __syncthreads();
        bf16x8 af[4], bfr[NI];
        #pragma unroll
        for (int mi = 0; mi < 4; mi++)
            af[mi] = *(const bf16x8*)&As[(wm + mi * 16 + lr) * 32 + lg * 8];
        #pragma unroll
        for (int ni = 0; ni < NI; ni++)
            bfr[ni] = *(const bf16x8*)&Bs[(wn + ni * 16 + lr) * 32 + lg * 8];
        #pragma unroll
        for (int mi = 0; mi < 4; mi++)
            #pragma unroll
            for (int ni = 0; ni < NI; ni++)
                acc[mi][ni] = __builtin_amdgcn_mfma_f32_16x16x32_bf16(af[mi], bfr[ni], acc[mi][ni], 0, 0, 0);
    }
    #pragma unroll
    for (int mi = 0; mi < 4; mi++)
    #pragma unroll
    for (int ni = 0; ni < NI; ni++)
    #pragma unroll
    for (int r = 0; r < 4; r++) {
        long row = m0 + wm + mi * 16 + lg * 4 + r;
        long col = n0 + wn + ni * 16 + lr;
        float v = acc[mi][ni][r];
        if (WRITE_BF16) ((short*)Cv)[row * N + col] = f2bf(v);
        else            ((float*)Cv)[row * N + col] = v;
    }
}

// ------- fused RMSNorm + partial RoPE for Q and K in one launch -------------
__global__ __launch_bounds__(256) void norm_rope2_kernel(
    const short* __restrict__ C, short* __restrict__ qout, short* __restrict__ kout,
    const float* __restrict__ qw, const float* __restrict__ kw,
    const float* __restrict__ cosb, const float* __restrict__ sinb) {
    int bid = blockIdx.x;
    bool isQ = bid < 8192;
    int H        = isQ ? 8 : 2;
    long cofs    = isQ ? 0L : 2048L;
    const float* w = isQ ? qw : kw;
    short* out   = isQ ? qout : kout;
    long ob      = isQ ? 4194304L : 1048576L;
    long oh      = isQ ? 256L : 524288L;
    long os      = isQ ? 2048L : 256L;
    float scale  = isQ ? 0.0625f : 1.0f;
    int vec = (isQ ? bid : bid - 8192) * 4 + (threadIdx.x >> 6);
    int lane = threadIdx.x & 63;
    int token = vec / H, head = vec % H;
    int b = token / S_LEN, s = token % S_LEN;

    bf16x4 xv = *(const bf16x4*)(C + (long)token * 3072 + cofs + head * 256 + lane * 4);
    float x0 = bf2f(xv[0]), x1 = bf2f(xv[1]), x2 = bf2f(xv[2]), x3 = bf2f(xv[3]);
    float ss = x0 * x0 + x1 * x1 + x2 * x2 + x3 * x3;
    #pragma unroll
    for (int m = 1; m < 64; m <<= 1) ss += __shfl_xor(ss, m);
    float inv = rsqrtf(ss * (1.f / 256.f) + 1e-6f);

    float4 wv = *(const float4*)(w + lane * 4);
    float y0 = x0 * inv * (1.f + wv.x);
    float y1 = x1 * inv * (1.f + wv.y);
    float y2 = x2 * inv * (1.f + wv.z);
    float y3 = x3 * inv * (1.f + wv.w);

    if (lane < 16) {
        float2 c = *(const float2*)&cosb[s * 32 + lane * 2];
        float2 sn = *(const float2*)&sinb[s * 32 + lane * 2];
        float a0 = y0 * c.x - y1 * sn.x, b0 = y0 * sn.x + y1 * c.x;
        float a1 = y2 * c.y - y3 * sn.y, b1 = y2 * sn.y + y3 * c.y;
        y0 = a0; y1 = b0; y2 = a1; y3 = b1;
    }
    y0 *= scale; y1 *= scale; y2 *= scale; y3 *= scale;
    long oidx = (long)b * ob + (long)head * oh + (long)s * os + lane * 4;
    bf16x4 o; o[0] = f2bf(y0); o[1] = f2bf(y1); o[2] = f2bf(y2); o[3] = f2bf(y3);
    *(bf16x4*)(out + oidx) = o;
}

// ---------------- V transpose: C[token][2560+kv*256+d] -> vr[b][kv][d][s] ---
__global__ __launch_bounds__(256) void transpose_v_kernel(const short* __restrict__ C,
                                                          short* __restrict__ vr) {
    __shared__ short tile[64][65];
    int s0 = blockIdx.x * 64, d0 = blockIdx.y * 64;
    int bkv = blockIdx.z; int b = bkv >> 1, kv = bkv & 1;
    int t = threadIdx.x;
    #pragma unroll
    for (int i = 0; i < 16; i++) {
        int flat = i * 256 + t; int si = flat >> 6, di = flat & 63;
        tile[si][di] = C[(long)(b * S_LEN + s0 + si) * 3072 + 2560 + kv * 256 + d0 + di];
    }
    __syncthreads();
    #pragma unroll
    for (int i = 0; i < 16; i++) {
        int flat = i * 256 + t; int di = flat >> 6, si = flat & 63;
        vr[(long)(bkv * 256 + d0 + di) * S_LEN + s0 + si] = tile[si][di];
    }
}

// ---------------- flash attention: r8 body + BALANCED CU pairing ------------
// 4 waves (2 q-groups x 2 key parities), 64 q rows/block, 2 blocks/CU.
// Phase: vmcnt(0)|BAR|compute|BAR|stage(ph+1).
// Blocks rm and rm+256 land on the same CU (round-robin dispatch) and get
// j = 31-jj and jj -> per-CU phase total == 33 (was 18..48 heavy-first).
__global__ __launch_bounds__(256, 2) void flash_kernel(const short* __restrict__ Q,
                                                       const short* __restrict__ Kt,
                                                       const short* __restrict__ Vt,
                                                       short* __restrict__ O) {
    // [0,32K): K tiles (parity p at p*16KB); [32K,64K): V tiles; epilogue reuses
    __shared__ __align__(16) char smem[66048];

    int idx = blockIdx.x;
    int half = idx >> 8, rm = idx & 255;
    int xcd = rm & 7, slot = rm >> 3;        // consecutive blocks -> XCD round-robin
    int bh = xcd * 2 + (slot & 1);           // 2 bh per XCD -> 4MB KV in its L2
    int jj = slot >> 1;                      // 0..15
    int j  = half ? jj : (31 - jj);          // CU pair (rm, rm+256): j sums to 31
    int h = bh & 7, b = bh >> 3;
    int kv = h >> 2;
    int t = threadIdx.x, lane = t & 63, w = t >> 6;
    int g = w >> 1, p = w & 1;               // q-group, key parity
    int ln = lane & 31, hi = lane >> 5;
    int q0 = j * 64 + g * 32;
    int qg = q0 + ln;                        // this lane's q row (score column)

    const short* Kb = Kt + (long)(b * NKV + kv) * S_LEN * HD;
    const short* Vb = Vt + (long)(b * NKV + kv) * HD * S_LEN;

    // Q fragments in registers: Q[q=ln][dc*16 + hi*8 + e]
    bf16x8 qf[16];
    {
        const short* qrow = Q + ((long)(b * S_LEN + qg) * NHQ + h) * HD + hi * 8;
        #pragma unroll
        for (int dc = 0; dc < 16; dc++) qf[dc] = *(const bf16x8*)&qrow[dc * 16];
    }

    f32x16 acc[8];
    #pragma unroll
    for (int i = 0; i < 8; i++)
        #pragma unroll
        for (int jj2 = 0; jj2 < 16; jj2++) acc[i][jj2] = 0.f;
    float m = -1e30f, l = 0.f;

    // stage tiles {2*ph2, 2*ph2+1} into parity slots 0/1 (16 loads/thread)
    auto stage = [&](int ph2) {
        #pragma unroll
        for (int pp = 0; pp < 2; pp++) {
            int k0s = (2 * ph2 + pp) * KVB;
            short* Ktile = (short*)(smem + pp * 16384);
            short* Vtile = (short*)(smem + 32768 + pp * 16384);
            #pragma unroll
            for (int c = 0; c < 4; c++) {
                int o = c * 4096 + w * 1024 + lane * 16;   // byte offset in tile
                int key = o >> 9, db = o & 511;
                gload16(Kb + (long)(k0s + key) * HD + ((db ^ ((key & 7) << 4)) >> 1),
                        Ktile + (c * 4096 + w * 1024) / 2);
                int d = o >> 6, kb = o & 63;
                gload16(Vb + (long)d * S_LEN + k0s + ((kb ^ ((d & 6) << 3)) >> 1),
                        Vtile + (c * 4096 + w * 1024) / 2);
            }
        }
    };

    auto compute = [&](int k0) {
        const char* Ks = (const char*)smem + p * 16384;
        const char* Vs = (const char*)smem + 32768 + p * 16384;
        // ---- QK^T (swapped): s = K * Q, D[key][q]; 2 chains ----
        f32x16 sA, sB;
        #pragma unroll
        for (int r = 0; r < 16; r++) { sA[r] = 0.f; sB[r] = 0.f; }
        __builtin_amdgcn_s_setprio(1);
        #pragma unroll
        for (int dc = 0; dc < 16; dc += 2) {
            int kb0 = (dc * 32 + hi * 16) ^ ((ln & 7) << 4);
            int kb1 = ((dc + 1) * 32 + hi * 16) ^ ((ln & 7) << 4);
            bf16x8 kf0 = *(const bf16x8*)(Ks + ln * 512 + kb0);
            bf16x8 kf1 = *(const bf16x8*)(Ks + ln * 512 + kb1);
            sA = __builtin_amdgcn_mfma_f32_32x32x16_bf16(kf0, qf[dc],     sA, 0, 0, 0);
            sB = __builtin_amdgcn_mfma_f32_32x32x16_bf16(kf1, qf[dc + 1], sB, 0, 0, 0);
        }
        __builtin_amdgcn_s_setprio(0);
        f32x16 s;
        #pragma unroll
        for (int r = 0; r < 16; r++) s[r] = sA[r] + sB[r];

        // ---- mask + online softmax, fully in-register ----
        if (k0 + KVB - 1 > q0) {
            #pragma unroll
            for (int r = 0; r < 16; r++) {
                int key_g = k0 + (r & 3) + 8 * (r >> 2) + 4 * hi;
                if (key_g > qg) s[r] = -1e30f;
            }
        }
        float mt = s[0];
        #pragma unroll
        for (int r = 1; r < 16; r++) mt = fmaxf(mt, s[r]);
        mt = fmaxf(mt, __shfl_xor(mt, 32));
        float mn = m;
        if (!__all(mt <= m + 8.f)) {           // defer-max (T13)
            mn = fmaxf(m, mt);
            float f = __expf(m - mn);
            m = mn;
            float fr[16];
            #pragma unroll
            for (int r = 0; r < 16; r++)
                fr[r] = bperm((r & 3) + 8 * (r >> 2) + 4 * hi, f);
            #pragma unroll
            for (int i = 0; i < 8; i++)
                #pragma unroll
                for (int r = 0; r < 16; r++) acc[i][r] *= fr[r];
            l *= f;
        }
        float pr[16], ps = 0.f;
        #pragma unroll
        for (int r = 0; r < 16; r++) { pr[r] = __expf(s[r] - mn); ps += pr[r]; }
        ps += __shfl_xor(ps, 32);
        l += ps;

        // ---- P -> bf16 A-fragments via cvt_pk + permlane32_swap (T12) ----
        unsigned pw[8];
        #pragma unroll
        for (int kc = 0; kc < 2; kc++) {
            unsigned X = cvtpk(pr[kc * 8 + 0], pr[kc * 8 + 1]);
            unsigned Y = cvtpk(pr[kc * 8 + 4], pr[kc * 8 + 5]);
            unsigned Z = cvtpk(pr[kc * 8 + 2], pr[kc * 8 + 3]);
            unsigned W = cvtpk(pr[kc * 8 + 6], pr[kc * 8 + 7]);
            asm volatile("v_permlane32_swap_b32 %0, %1" : "+v"(X), "+v"(Y));
            asm volatile("v_permlane32_swap_b32 %0, %1" : "+v"(Z), "+v"(W));
            pw[kc * 4 + 0] = X; pw[kc * 4 + 1] = Z;
            pw[kc * 4 + 2] = Y; pw[kc * 4 + 3] = W;
        }
        u32x4 w0v = {pw[0], pw[1], pw[2], pw[3]};
        u32x4 w1v = {pw[4], pw[5], pw[6], pw[7]};
        bf16x8 pa0 = __builtin_bit_cast(bf16x8, w0v);
        bf16x8 pa1 = __builtin_bit_cast(bf16x8, w1v);

        // ---- PV: acc[db] += P * V, D[q][d], lane owns d column ----
        __builtin_amdgcn_s_setprio(1);
        #pragma unroll
        for (int db = 0; db < 8; db++) {
            int drow = db * 32 + ln;
            int sw = (drow & 6) << 3;
            bf16x8 vf0 = *(const bf16x8*)(Vs + drow * 64 + ((hi * 16) ^ sw));
            bf16x8 vf1 = *(const bf16x8*)(Vs + drow * 64 + ((32 + hi * 16) ^ sw));
            acc[db] = __builtin_amdgcn_mfma_f32_32x32x16_bf16(pa0, vf0, acc[db], 0, 0, 0);
            acc[db] = __builtin_amdgcn_mfma_f32_32x32x16_bf16(pa1, vf1, acc[db], 0, 0, 0);
        }
        __builtin_amdgcn_s_setprio(0);
    };

    stage(0);
    for (int ph = 0; ph <= j; ph++) {
        asm volatile("s_waitcnt vmcnt(0)" ::: "memory");
        __builtin_amdgcn_s_barrier();
        int k0 = (2 * ph + p) * KVB;
        if (k0 <= q0 + 31) compute(k0);      // skip only fully-masked diagonal tile
        __builtin_amdgcn_s_barrier();
        if (ph < j) stage(ph + 1);
        __builtin_amdgcn_sched_barrier(0);
    }

    // ---- parity merge epilogue (staging LDS is dead) ----
    float* accb = (float*)smem;                 // [g][128][64] f32
    float* mlb  = (float*)(smem + 65536);       // m: [0,64), l: [64,128)
    if (p == 1) {
        #pragma unroll
        for (int db = 0; db < 8; db++)
            #pragma unroll
            for (int r = 0; r < 16; r++)
                accb[g * 8192 + (db * 16 + r) * 64 + hi * 32 + ln] = acc[db][r];
        if (hi == 0) { mlb[g * 32 + ln] = m; mlb[64 + g * 32 + ln] = l; }
    }
    __syncthreads();
    if (p == 0) {
        float m1 = mlb[g * 32 + ln], l1 = mlb[64 + g * 32 + ln];
        float M  = fmaxf(m, m1);
        float f0 = __expf(m - M), f1 = __expf(m1 - M);
        float lt = l * f0 + l1 * f1;
        float w0 = f0 / lt, w1 = f1 / lt;
        float fr0[16], fr1[16];
        #pragma unroll
        for (int r = 0; r < 16; r++) {
            int crow = (r & 3) + 8 * (r >> 2) + 4 * hi;
            fr0[r] = bperm(crow, w0);
            fr1[r] = bperm(crow, w1);
        }
        #pragma unroll
        for (int db = 0; db < 8; db++)
            #pragma unroll
            for (int r = 0; r < 16; r++) {
                float a1 = accb[g * 8192 + (db * 16 + r) * 64 + hi * 32 + ln];
                int qrow = q0 + (r & 3) + 8 * (r >> 2) + 4 * hi;
                O[(long)(b * S_LEN + qrow) * 2048 + h * HD + db * 32 + ln] =
                    f2bf(acc[db][r] * fr0[r] + a1 * fr1[r]);
            }
    }
}

extern "C" void kernel_launch(void* const* d_in, const int* in_sizes, int n_in,
                              void* d_out, int out_size, void* d_ws, size_t ws_size,
                              hipStream_t stream) {
    const float* x    = (const float*)d_in[0];
    const float* cosb = (const float*)d_in[1];
    const float* sinb = (const float*)d_in[2];
    // d_in[3] = mask: equivalent to causal; computed analytically in-kernel
    const float* wq   = (const float*)d_in[4];
    const float* wk   = (const float*)d_in[5];
    const float* wv   = (const float*)d_in[6];
    const float* wo   = (const float*)d_in[7];
    const float* qnw  = (const float*)d_in[8];
    const float* knw  = (const float*)d_in[9];
    float* out = (float*)d_out;

    char* ws = (char*)d_ws;
    short* xb   = (short*)(ws + 0);          // 4096x512 bf16               [0, 4194304)
    short* wfus = (short*)(ws + 4194304);    // [3072][512] wq|wk|wv^T      [4194304, 7340032)
    short* wot  = (short*)(ws + 7340032);    // [512][2048] wo^T            [7340032, 9437184)
    short* C    = (short*)(ws + 9437184);    // 4096x3072 fused QKV out     [9437184, 34603008)
    short* ao   = (short*)(ws + 9437184);    // flash out aliases C (C dead by then)
    short* qro  = (short*)(ws + 34603008);   // 4096x2048 roped Q           [34603008, 51380224)
    short* kr   = (short*)(ws + 51380224);   // [b][kv][s][d] 4 MB          [51380224, 55574528)
    short* vr   = (short*)(ws + 55574528);   // [b][kv][d][s] 4 MB          [55574528, 59768832)

    cvt_kernel<<<2048, 256, 0, stream>>>(x, xb, 2097152);
    wt_all_kernel<<<640, 256, 0, stream>>>(wq, wk, wv, wo, wfus, wot);

    // fused QKV projection: C[4096][3072]
    gemm_bt<128, 1><<<dim3(24, 32), 256, 0, stream>>>(xb, wfus, C, 4096, 3072, 512);

    // Q (scale 1/16 folded) + K norm/rope in one launch
    norm_rope2_kernel<<<10240, 256, 0, stream>>>(C, qro, kr, qnw, knw, cosb, sinb);
    transpose_v_kernel<<<dim3(32, 4, 4), 256, 0, stream>>>(C, vr);

    flash_kernel<<<512, 256, 0, stream>>>(qro, kr, vr, ao);

    gemm_bt<64, 0><<<dim3(8, 32), 256, 0, stream>>>(ao, wot, out, 4096, 512, 2048);
}

// Round 18
// 186.025 us; speedup vs baseline: 1.1207x; 1.0682x over previous
//
#include <hip/hip_runtime.h>

#define S_LEN 2048
#define NHQ 8
#define NKV 2
#define HD 256
#define KVB 32

typedef __attribute__((ext_vector_type(8))) short bf16x8;
typedef __attribute__((ext_vector_type(4))) short bf16x4;
typedef __attribute__((ext_vector_type(4))) float f32x4;
typedef __attribute__((ext_vector_type(16))) float f32x16;
typedef __attribute__((ext_vector_type(4))) unsigned u32x4;

__device__ __forceinline__ short f2bf(float f) {
    unsigned u = __builtin_bit_cast(unsigned, f);
    u += 0x7FFFu + ((u >> 16) & 1u);
    return (short)(u >> 16);
}
__device__ __forceinline__ float bf2f(short s) {
    unsigned u = ((unsigned)(unsigned short)s) << 16;
    return __builtin_bit_cast(float, u);
}
__device__ __forceinline__ unsigned cvtpk(float a, float b) {
    unsigned r;
    asm("v_cvt_pk_bf16_f32 %0, %1, %2" : "=v"(r) : "v"(a), "v"(b));
    return r;
}
__device__ __forceinline__ void gload16(const short* g, short* l) {
    __builtin_amdgcn_global_load_lds((const __attribute__((address_space(1))) unsigned*)g,
                                     (__attribute__((address_space(3))) unsigned*)l, 16, 0, 0);
}
__device__ __forceinline__ float bperm(int srclane, float v) {
    return __builtin_bit_cast(float,
        __builtin_amdgcn_ds_bpermute(srclane * 4, __builtin_bit_cast(int, v)));
}

// ---------------- fp32 -> bf16 convert ----------------
__global__ __launch_bounds__(256) void cvt_kernel(const float* __restrict__ in,
                                                  short* __restrict__ out, int n) {
    int i = (blockIdx.x * 256 + threadIdx.x) * 4;
    if (i + 3 < n) {
        float4 f = *(const float4*)(in + i);
        bf16x4 o;
        o[0] = f2bf(f.x); o[1] = f2bf(f.y); o[2] = f2bf(f.z); o[3] = f2bf(f.w);
        *(bf16x4*)(out + i) = o;
    }
}

// ------- fused weight prep: all four W[K][N] -> bf16 Wt[N][K] transposes ----
__global__ __launch_bounds__(256) void wt_all_kernel(const float* __restrict__ wq,
                                                     const float* __restrict__ wk,
                                                     const float* __restrict__ wv,
                                                     const float* __restrict__ wo,
                                                     short* __restrict__ wfus,
                                                     short* __restrict__ wot) {
    __shared__ short tile[64][72];
    int bid = blockIdx.x;
    const float* in; short* out; int K, N, nx, base;
    if (bid < 256)      { in = wq; out = wfus;             K = 512;  N = 2048; nx = 32; base = 0;   }
    else if (bid < 320) { in = wk; out = wfus + 2048 * 512; K = 512;  N = 512;  nx = 8;  base = 256; }
    else if (bid < 384) { in = wv; out = wfus + 2560 * 512; K = 512;  N = 512;  nx = 8;  base = 320; }
    else                { in = wo; out = wot;              K = 2048; N = 512;  nx = 8;  base = 384; }
    int lb = bid - base;
    int n0 = (lb % nx) * 64, k0 = (lb / nx) * 64;
    int t = threadIdx.x;
    #pragma unroll
    for (int i = 0; i < 16; i++) {
        int flat = i * 256 + t; int r = flat >> 6, c = flat & 63;
        tile[r][c] = f2bf(in[(long)(k0 + r) * N + n0 + c]);
    }
    __syncthreads();
    #pragma unroll
    for (int i = 0; i < 16; i++) {
        int flat = i * 256 + t; int r = flat >> 6, c = flat & 63;
        out[(long)(n0 + r) * K + k0 + c] = tile[c][r];
    }
}

// -------- 2-phase dbuf GEMM (catalog T3 minimum): C = A[M][K] @ Bt[N][K]^T --
// Per K-tile: {STAGE(next buf); ds_read+MFMA(cur); vmcnt(0); s_barrier}.
// Stage latency hides under compute; 1 barrier/tile (was 2 + full drain).
template<int BN, int WRITE_BF16>
__global__ __launch_bounds__(256) void gemm_bt(const short* __restrict__ A,
                                               const short* __restrict__ Bt,
                                               void* __restrict__ Cv,
                                               int M, int N, int K) {
    constexpr int NI = BN / 32;          // B-frags per wave
    __shared__ short As[2][128 * 32];
    __shared__ short Bs[2][BN * 32];
    const int t = threadIdx.x;
    const int lane = t & 63, w = t >> 6;
    const int lr = lane & 15, lg = lane >> 4;
    const int m0 = blockIdx.y * 128, n0 = blockIdx.x * BN;
    const int wm = (w >> 1) * 64, wn = (w & 1) * (BN / 2);

    f32x4 acc[4][NI];
    #pragma unroll
    for (int i = 0; i < 4; i++)
        #pragma unroll
        for (int j = 0; j < NI; j++) acc[i][j] = (f32x4){0.f, 0.f, 0.f, 0.f};

    auto stage = [&](int buf, int kt) {
        int k0 = kt * 32;
        #pragma unroll
        for (int r = 0; r < 2; r++) {            // A tile: 128x32 = 8 KB
            int sbase = r * 2048 + w * 512;
            int off = sbase + lane * 8;
            int srow = off >> 5, scol = off & 31;
            gload16(A + (long)(m0 + srow) * K + k0 + scol, &As[buf][sbase]);
        }
        #pragma unroll
        for (int r = 0; r < BN / 64; r++) {      // B tile: BNx32
            int sbase = r * 2048 + w * 512;
            int off = sbase + lane * 8;
            int srow = off >> 5, scol = off & 31;
            gload16(Bt + (long)(n0 + srow) * K + k0 + scol, &Bs[buf][sbase]);
        }
    };

    const int nt = K / 32;
    stage(0, 0);
    asm volatile("s_waitcnt vmcnt(0)" ::: "memory");
    __builtin_amdgcn_s_barrier();

    for (int kt = 0; kt < nt; kt++) {
        int cur = kt & 1;
        if (kt + 1 < nt) stage(cur ^ 1, kt + 1);     // issue-early (overlaps MFMA)
        bf16x8 af[4], bfr[NI];
        #pragma unroll
        for (int mi = 0; mi < 4; mi++)
            af[mi] = *(const bf16x8*)&As[cur][(wm + mi * 16 + lr) * 32 + lg * 8];
        #pragma unroll
        for (int ni = 0; ni < NI; ni++)
            bfr[ni] = *(const bf16x8*)&Bs[cur][(wn + ni * 16 + lr) * 32 + lg * 8];
        __builtin_amdgcn_s_setprio(1);
        #pragma unroll
        for (int mi = 0; mi < 4; mi++)
            #pragma unroll
            for (int ni = 0; ni < NI; ni++)
                acc[mi][ni] = __builtin_amdgcn_mfma_f32_16x16x32_bf16(af[mi], bfr[ni], acc[mi][ni], 0, 0, 0);
        __builtin_amdgcn_s_setprio(0);
        asm volatile("s_waitcnt vmcnt(0)" ::: "memory");   // next tile landed
        __builtin_amdgcn_s_barrier();
    }

    #pragma unroll
    for (int mi = 0; mi < 4; mi++)
    #pragma unroll
    for (int ni = 0; ni < NI; ni++)
    #pragma unroll
    for (int r = 0; r < 4; r++) {
        long row = m0 + wm + mi * 16 + lg * 4 + r;
        long col = n0 + wn + ni * 16 + lr;
        float v = acc[mi][ni][r];
        if (WRITE_BF16) ((short*)Cv)[row * N + col] = f2bf(v);
        else            ((float*)Cv)[row * N + col] = v;
    }
}

// ------- fused RMSNorm + partial RoPE for Q and K in one launch -------------
__global__ __launch_bounds__(256) void norm_rope2_kernel(
    const short* __restrict__ C, short* __restrict__ qout, short* __restrict__ kout,
    const float* __restrict__ qw, const float* __restrict__ kw,
    const float* __restrict__ cosb, const float* __restrict__ sinb) {
    int bid = blockIdx.x;
    bool isQ = bid < 8192;
    int H        = isQ ? 8 : 2;
    long cofs    = isQ ? 0L : 2048L;
    const float* w = isQ ? qw : kw;
    short* out   = isQ ? qout : kout;
    long ob      = isQ ? 4194304L : 1048576L;
    long oh      = isQ ? 256L : 524288L;
    long os      = isQ ? 2048L : 256L;
    float scale  = isQ ? 0.0625f : 1.0f;
    int vec = (isQ ? bid : bid - 8192) * 4 + (threadIdx.x >> 6);
    int lane = threadIdx.x & 63;
    int token = vec / H, head = vec % H;
    int b = token / S_LEN, s = token % S_LEN;

    bf16x4 xv = *(const bf16x4*)(C + (long)token * 3072 + cofs + head * 256 + lane * 4);
    float x0 = bf2f(xv[0]), x1 = bf2f(xv[1]), x2 = bf2f(xv[2]), x3 = bf2f(xv[3]);
    float ss = x0 * x0 + x1 * x1 + x2 * x2 + x3 * x3;
    #pragma unroll
    for (int m = 1; m < 64; m <<= 1) ss += __shfl_xor(ss, m);
    float inv = rsqrtf(ss * (1.f / 256.f) + 1e-6f);

    float4 wv = *(const float4*)(w + lane * 4);
    float y0 = x0 * inv * (1.f + wv.x);
    float y1 = x1 * inv * (1.f + wv.y);
    float y2 = x2 * inv * (1.f + wv.z);
    float y3 = x3 * inv * (1.f + wv.w);

    if (lane < 16) {
        float2 c = *(const float2*)&cosb[s * 32 + lane * 2];
        float2 sn = *(const float2*)&sinb[s * 32 + lane * 2];
        float a0 = y0 * c.x - y1 * sn.x, b0 = y0 * sn.x + y1 * c.x;
        float a1 = y2 * c.y - y3 * sn.y, b1 = y2 * sn.y + y3 * c.y;
        y0 = a0; y1 = b0; y2 = a1; y3 = b1;
    }
    y0 *= scale; y1 *= scale; y2 *= scale; y3 *= scale;
    long oidx = (long)b * ob + (long)head * oh + (long)s * os + lane * 4;
    bf16x4 o; o[0] = f2bf(y0); o[1] = f2bf(y1); o[2] = f2bf(y2); o[3] = f2bf(y3);
    *(bf16x4*)(out + oidx) = o;
}

// ---------------- V transpose: C[token][2560+kv*256+d] -> vr[b][kv][d][s] ---
__global__ __launch_bounds__(256) void transpose_v_kernel(const short* __restrict__ C,
                                                          short* __restrict__ vr) {
    __shared__ short tile[64][65];
    int s0 = blockIdx.x * 64, d0 = blockIdx.y * 64;
    int bkv = blockIdx.z; int b = bkv >> 1, kv = bkv & 1;
    int t = threadIdx.x;
    #pragma unroll
    for (int i = 0; i < 16; i++) {
        int flat = i * 256 + t; int si = flat >> 6, di = flat & 63;
        tile[si][di] = C[(long)(b * S_LEN + s0 + si) * 3072 + 2560 + kv * 256 + d0 + di];
    }
    __syncthreads();
    #pragma unroll
    for (int i = 0; i < 16; i++) {
        int flat = i * 256 + t; int di = flat >> 6, si = flat & 63;
        vr[(long)(bkv * 256 + d0 + di) * S_LEN + s0 + si] = tile[si][di];
    }
}

// ---------------- flash attention: byte-exact r8/r15 (best measured) --------
// 4 waves (2 q-groups x 2 key parities), 64 q rows/block, 2 blocks/CU.
// Phase: vmcnt(0)|BAR|compute|BAR|stage(ph+1). Heavy-first XCD mapping.
__global__ __launch_bounds__(256, 2) void flash_kernel(const short* __restrict__ Q,
                                                       const short* __restrict__ Kt,
                                                       const short* __restrict__ Vt,
                                                       short* __restrict__ O) {
    // [0,32K): K tiles (parity p at p*16KB); [32K,64K): V tiles; epilogue reuses
    __shared__ __align__(16) char smem[66048];

    int idx = blockIdx.x;
    int xcd = idx & 7, slot = idx >> 3;      // consecutive blocks -> XCD round-robin
    int bh = xcd * 2 + (slot & 1);           // 2 bh per XCD -> 4MB KV in its L2
    int j  = 31 - (slot >> 1);               // chunk 0..31, heavy first
    int h = bh & 7, b = bh >> 3;
    int kv = h >> 2;
    int t = threadIdx.x, lane = t & 63, w = t >> 6;
    int g = w >> 1, p = w & 1;               // q-group, key parity
    int ln = lane & 31, hi = lane >> 5;
    int q0 = j * 64 + g * 32;
    int qg = q0 + ln;                        // this lane's q row (score column)

    const short* Kb = Kt + (long)(b * NKV + kv) * S_LEN * HD;
    const short* Vb = Vt + (long)(b * NKV + kv) * HD * S_LEN;

    // Q fragments in registers: Q[q=ln][dc*16 + hi*8 + e]
    bf16x8 qf[16];
    {
        const short* qrow = Q + ((long)(b * S_LEN + qg) * NHQ + h) * HD + hi * 8;
        #pragma unroll
        for (int dc = 0; dc < 16; dc++) qf[dc] = *(const bf16x8*)&qrow[dc * 16];
    }

    f32x16 acc[8];
    #pragma unroll
    for (int i = 0; i < 8; i++)
        #pragma unroll
        for (int jj = 0; jj < 16; jj++) acc[i][jj] = 0.f;
    float m = -1e30f, l = 0.f;

    // stage tiles {2*ph2, 2*ph2+1} into parity slots 0/1 (16 loads/thread)
    auto stage = [&](int ph2) {
        #pragma unroll
        for (int pp = 0; pp < 2; pp++) {
            int k0s = (2 * ph2 + pp) * KVB;
            short* Ktile = (short*)(smem + pp * 16384);
            short* Vtile = (short*)(smem + 32768 + pp * 16384);
            #pragma unroll
            for (int c = 0; c < 4; c++) {
                int o = c * 4096 + w * 1024 + lane * 16;   // byte offset in tile
                int key = o >> 9, db = o & 511;
                gload16(Kb + (long)(k0s + key) * HD + ((db ^ ((key & 7) << 4)) >> 1),
                        Ktile + (c * 4096 + w * 1024) / 2);
                int d = o >> 6, kb = o & 63;
                gload16(Vb + (long)d * S_LEN + k0s + ((kb ^ ((d & 6) << 3)) >> 1),
                        Vtile + (c * 4096 + w * 1024) / 2);
            }
        }
    };

    auto compute = [&](int k0) {
        const char* Ks = (const char*)smem + p * 16384;
        const char* Vs = (const char*)smem + 32768 + p * 16384;
        // ---- QK^T (swapped): s = K * Q, D[key][q]; 2 chains ----
        f32x16 sA, sB;
        #pragma unroll
        for (int r = 0; r < 16; r++) { sA[r] = 0.f; sB[r] = 0.f; }
        __builtin_amdgcn_s_setprio(1);
        #pragma unroll
        for (int dc = 0; dc < 16; dc += 2) {
            int kb0 = (dc * 32 + hi * 16) ^ ((ln & 7) << 4);
            int kb1 = ((dc + 1) * 32 + hi * 16) ^ ((ln & 7) << 4);
            bf16x8 kf0 = *(const bf16x8*)(Ks + ln * 512 + kb0);
            bf16x8 kf1 = *(const bf16x8*)(Ks + ln * 512 + kb1);
            sA = __builtin_amdgcn_mfma_f32_32x32x16_bf16(kf0, qf[dc],     sA, 0, 0, 0);
            sB = __builtin_amdgcn_mfma_f32_32x32x16_bf16(kf1, qf[dc + 1], sB, 0, 0, 0);
        }
        __builtin_amdgcn_s_setprio(0);
        f32x16 s;
        #pragma unroll
        for (int r = 0; r < 16; r++) s[r] = sA[r] + sB[r];

        // ---- mask + online softmax, fully in-register ----
        if (k0 + KVB - 1 > q0) {
            #pragma unroll
            for (int r = 0; r < 16; r++) {
                int key_g = k0 + (r & 3) + 8 * (r >> 2) + 4 * hi;
                if (key_g > qg) s[r] = -1e30f;
            }
        }
        float mt = s[0];
        #pragma unroll
        for (int r = 1; r < 16; r++) mt = fmaxf(mt, s[r]);
        mt = fmaxf(mt, __shfl_xor(mt, 32));
        float mn = m;
        if (!__all(mt <= m + 8.f)) {           // defer-max (T13)
            mn = fmaxf(m, mt);
            float f = __expf(m - mn);
            m = mn;
            float fr[16];
            #pragma unroll
            for (int r = 0; r < 16; r++)
                fr[r] = bperm((r & 3) + 8 * (r >> 2) + 4 * hi, f);
            #pragma unroll
            for (int i = 0; i < 8; i++)
                #pragma unroll
                for (int r = 0; r < 16; r++) acc[i][r] *= fr[r];
            l *= f;
        }
        float pr[16], ps = 0.f;
        #pragma unroll
        for (int r = 0; r < 16; r++) { pr[r] = __expf(s[r] - mn); ps += pr[r]; }
        ps += __shfl_xor(ps, 32);
        l += ps;

        // ---- P -> bf16 A-fragments via cvt_pk + permlane32_swap (T12) ----
        unsigned pw[8];
        #pragma unroll
        for (int kc = 0; kc < 2; kc++) {
            unsigned X = cvtpk(pr[kc * 8 + 0], pr[kc * 8 + 1]);
            unsigned Y = cvtpk(pr[kc * 8 + 4], pr[kc * 8 + 5]);
            unsigned Z = cvtpk(pr[kc * 8 + 2], pr[kc * 8 + 3]);
            unsigned W = cvtpk(pr[kc * 8 + 6], pr[kc * 8 + 7]);
            asm volatile("v_permlane32_swap_b32 %0, %1" : "+v"(X), "+v"(Y));
            asm volatile("v_permlane32_swap_b32 %0, %1" : "+v"(Z), "+v"(W));
            pw[kc * 4 + 0] = X; pw[kc * 4 + 1] = Z;
            pw[kc * 4 + 2] = Y; pw[kc * 4 + 3] = W;
        }
        u32x4 w0v = {pw[0], pw[1], pw[2], pw[3]};
        u32x4 w1v = {pw[4], pw[5], pw[6], pw[7]};
        bf16x8 pa0 = __builtin_bit_cast(bf16x8, w0v);
        bf16x8 pa1 = __builtin_bit_cast(bf16x8, w1v);

        // ---- PV: acc[db] += P * V, D[q][d], lane owns d column ----
        __builtin_amdgcn_s_setprio(1);
        #pragma unroll
        for (int db = 0; db < 8; db++) {
            int drow = db * 32 + ln;
            int sw = (drow & 6) << 3;
            bf16x8 vf0 = *(const bf16x8*)(Vs + drow * 64 + ((hi * 16) ^ sw));
            bf16x8 vf1 = *(const bf16x8*)(Vs + drow * 64 + ((32 + hi * 16) ^ sw));
            acc[db] = __builtin_amdgcn_mfma_f32_32x32x16_bf16(pa0, vf0, acc[db], 0, 0, 0);
            acc[db] = __builtin_amdgcn_mfma_f32_32x32x16_bf16(pa1, vf1, acc[db], 0, 0, 0);
        }
        __builtin_amdgcn_s_setprio(0);
    };

    stage(0);
    for (int ph = 0; ph <= j; ph++) {
        asm volatile("s_waitcnt vmcnt(0)" ::: "memory");
        __builtin_amdgcn_s_barrier();
        int k0 = (2 * ph + p) * KVB;
        if (k0 <= q0 + 31) compute(k0);      // skip only fully-masked diagonal tile
        __builtin_amdgcn_s_barrier();
        if (ph < j) stage(ph + 1);
        __builtin_amdgcn_sched_barrier(0);
    }

    // ---- parity merge epilogue (staging LDS is dead) ----
    float* accb = (float*)smem;                 // [g][128][64] f32
    float* mlb  = (float*)(smem + 65536);       // m: [0,64), l: [64,128)
    if (p == 1) {
        #pragma unroll
        for (int db = 0; db < 8; db++)
            #pragma unroll
            for (int r = 0; r < 16; r++)
                accb[g * 8192 + (db * 16 + r) * 64 + hi * 32 + ln] = acc[db][r];
        if (hi == 0) { mlb[g * 32 + ln] = m; mlb[64 + g * 32 + ln] = l; }
    }
    __syncthreads();
    if (p == 0) {
        float m1 = mlb[g * 32 + ln], l1 = mlb[64 + g * 32 + ln];
        float M  = fmaxf(m, m1);
        float f0 = __expf(m - M), f1 = __expf(m1 - M);
        float lt = l * f0 + l1 * f1;
        float w0 = f0 / lt, w1 = f1 / lt;
        float fr0[16], fr1[16];
        #pragma unroll
        for (int r = 0; r < 16; r++) {
            int crow = (r & 3) + 8 * (r >> 2) + 4 * hi;
            fr0[r] = bperm(crow, w0);
            fr1[r] = bperm(crow, w1);
        }
        #pragma unroll
        for (int db = 0; db < 8; db++)
            #pragma unroll
            for (int r = 0; r < 16; r++) {
                float a1 = accb[g * 8192 + (db * 16 + r) * 64 + hi * 32 + ln];
                int qrow = q0 + (r & 3) + 8 * (r >> 2) + 4 * hi;
                O[(long)(b * S_LEN + qrow) * 2048 + h * HD + db * 32 + ln] =
                    f2bf(acc[db][r] * fr0[r] + a1 * fr1[r]);
            }
    }
}

extern "C" void kernel_launch(void* const* d_in, const int* in_sizes, int n_in,
                              void* d_out, int out_size, void* d_ws, size_t ws_size,
                              hipStream_t stream) {
    const float* x    = (const float*)d_in[0];
    const float* cosb = (const float*)d_in[1];
    const float* sinb = (const float*)d_in[2];
    // d_in[3] = mask: equivalent to causal; computed analytically in-kernel
    const float* wq   = (const float*)d_in[4];
    const float* wk   = (const float*)d_in[5];
    const float* wv   = (const float*)d_in[6];
    const float* wo   = (const float*)d_in[7];
    const float* qnw  = (const float*)d_in[8];
    const float* knw  = (const float*)d_in[9];
    float* out = (float*)d_out;

    char* ws = (char*)d_ws;
    short* xb   = (short*)(ws + 0);          // 4096x512 bf16               [0, 4194304)
    short* wfus = (short*)(ws + 4194304);    // [3072][512] wq|wk|wv^T      [4194304, 7340032)
    short* wot  = (short*)(ws + 7340032);    // [512][2048] wo^T            [7340032, 9437184)
    short* C    = (short*)(ws + 9437184);    // 4096x3072 fused QKV out     [9437184, 34603008)
    short* ao   = (short*)(ws + 9437184);    // flash out aliases C (C dead by then)
    short* qro  = (short*)(ws + 34603008);   // 4096x2048 roped Q           [34603008, 51380224)
    short* kr   = (short*)(ws + 51380224);   // [b][kv][s][d] 4 MB          [51380224, 55574528)
    short* vr   = (short*)(ws + 55574528);   // [b][kv][d][s] 4 MB          [55574528, 59768832)

    cvt_kernel<<<2048, 256, 0, stream>>>(x, xb, 2097152);
    wt_all_kernel<<<640, 256, 0, stream>>>(wq, wk, wv, wo, wfus, wot);

    // fused QKV projection: C[4096][3072]
    gemm_bt<128, 1><<<dim3(24, 32), 256, 0, stream>>>(xb, wfus, C, 4096, 3072, 512);

    // Q (scale 1/16 folded) + K norm/rope in one launch
    norm_rope2_kernel<<<10240, 256, 0, stream>>>(C, qro, kr, qnw, knw, cosb, sinb);
    transpose_v_kernel<<<dim3(32, 4, 4), 256, 0, stream>>>(C, vr);

    flash_kernel<<<512, 256, 0, stream>>>(qro, kr, vr, ao);

    gemm_bt<64, 0><<<dim3(8, 32), 256, 0, stream>>>(ao, wot, out, 4096, 512, 2048);
}

// Round 19
// 178.138 us; speedup vs baseline: 1.1703x; 1.0443x over previous
//
#include <hip/hip_runtime.h>

#define S_LEN 2048
#define NHQ 8
#define NKV 2
#define HD 256
#define KVB 32

typedef __attribute__((ext_vector_type(8))) short bf16x8;
typedef __attribute__((ext_vector_type(4))) short bf16x4;
typedef __attribute__((ext_vector_type(4))) float f32x4;
typedef __attribute__((ext_vector_type(16))) float f32x16;
typedef __attribute__((ext_vector_type(4))) unsigned u32x4;

__device__ __forceinline__ short f2bf(float f) {
    unsigned u = __builtin_bit_cast(unsigned, f);
    u += 0x7FFFu + ((u >> 16) & 1u);
    return (short)(u >> 16);
}
__device__ __forceinline__ float bf2f(short s) {
    unsigned u = ((unsigned)(unsigned short)s) << 16;
    return __builtin_bit_cast(float, u);
}
__device__ __forceinline__ unsigned cvtpk(float a, float b) {
    unsigned r;
    asm("v_cvt_pk_bf16_f32 %0, %1, %2" : "=v"(r) : "v"(a), "v"(b));
    return r;
}
__device__ __forceinline__ void gload16(const short* g, short* l) {
    __builtin_amdgcn_global_load_lds((const __attribute__((address_space(1))) unsigned*)g,
                                     (__attribute__((address_space(3))) unsigned*)l, 16, 0, 0);
}
__device__ __forceinline__ float bperm(int srclane, float v) {
    return __builtin_bit_cast(float,
        __builtin_amdgcn_ds_bpermute(srclane * 4, __builtin_bit_cast(int, v)));
}

// ---------------- fp32 -> bf16 convert ----------------
__global__ __launch_bounds__(256) void cvt_kernel(const float* __restrict__ in,
                                                  short* __restrict__ out, int n) {
    int i = (blockIdx.x * 256 + threadIdx.x) * 4;
    if (i + 3 < n) {
        float4 f = *(const float4*)(in + i);
        bf16x4 o;
        o[0] = f2bf(f.x); o[1] = f2bf(f.y); o[2] = f2bf(f.z); o[3] = f2bf(f.w);
        *(bf16x4*)(out + i) = o;
    }
}

// ------- fused weight prep: all four W[K][N] -> bf16 Wt[N][K] transposes ----
__global__ __launch_bounds__(256) void wt_all_kernel(const float* __restrict__ wq,
                                                     const float* __restrict__ wk,
                                                     const float* __restrict__ wv,
                                                     const float* __restrict__ wo,
                                                     short* __restrict__ wfus,
                                                     short* __restrict__ wot) {
    __shared__ short tile[64][72];
    int bid = blockIdx.x;
    const float* in; short* out; int K, N, nx, base;
    if (bid < 256)      { in = wq; out = wfus;             K = 512;  N = 2048; nx = 32; base = 0;   }
    else if (bid < 320) { in = wk; out = wfus + 2048 * 512; K = 512;  N = 512;  nx = 8;  base = 256; }
    else if (bid < 384) { in = wv; out = wfus + 2560 * 512; K = 512;  N = 512;  nx = 8;  base = 320; }
    else                { in = wo; out = wot;              K = 2048; N = 512;  nx = 8;  base = 384; }
    int lb = bid - base;
    int n0 = (lb % nx) * 64, k0 = (lb / nx) * 64;
    int t = threadIdx.x;
    #pragma unroll
    for (int i = 0; i < 16; i++) {
        int flat = i * 256 + t; int r = flat >> 6, c = flat & 63;
        tile[r][c] = f2bf(in[(long)(k0 + r) * N + n0 + c]);
    }
    __syncthreads();
    #pragma unroll
    for (int i = 0; i < 16; i++) {
        int flat = i * 256 + t; int r = flat >> 6, c = flat & 63;
        out[(long)(n0 + r) * K + k0 + c] = tile[c][r];
    }
}

// -------- 2-phase dbuf GEMM (T3): C[M][N] = A[M][K] @ Bt[N][K]^T ------------
// BM x BN tile, 2x2 waves each (BM/2 x BN/2). Per K-tile:
// {STAGE(next buf); ds_read+MFMA(cur); vmcnt(0); s_barrier}.
template<int BM, int BN, int WRITE_BF16>
__global__ __launch_bounds__(256) void gemm_bt(const short* __restrict__ A,
                                               const short* __restrict__ Bt,
                                               void* __restrict__ Cv,
                                               int M, int N, int K) {
    constexpr int MI = BM / 32;          // A-frags per wave
    constexpr int NI = BN / 32;          // B-frags per wave
    __shared__ short As[2][BM * 32];
    __shared__ short Bs[2][BN * 32];
    const int t = threadIdx.x;
    const int lane = t & 63, w = t >> 6;
    const int lr = lane & 15, lg = lane >> 4;
    const int m0 = blockIdx.y * BM, n0 = blockIdx.x * BN;
    const int wm = (w >> 1) * (BM / 2), wn = (w & 1) * (BN / 2);

    f32x4 acc[MI][NI];
    #pragma unroll
    for (int i = 0; i < MI; i++)
        #pragma unroll
        for (int j = 0; j < NI; j++) acc[i][j] = (f32x4){0.f, 0.f, 0.f, 0.f};

    auto stage = [&](int buf, int kt) {
        int k0 = kt * 32;
        #pragma unroll
        for (int r = 0; r < BM / 64; r++) {      // A tile: BMx32
            int sbase = r * 2048 + w * 512;
            int off = sbase + lane * 8;
            int srow = off >> 5, scol = off & 31;
            gload16(A + (long)(m0 + srow) * K + k0 + scol, &As[buf][sbase]);
        }
        #pragma unroll
        for (int r = 0; r < BN / 64; r++) {      // B tile: BNx32
            int sbase = r * 2048 + w * 512;
            int off = sbase + lane * 8;
            int srow = off >> 5, scol = off & 31;
            gload16(Bt + (long)(n0 + srow) * K + k0 + scol, &Bs[buf][sbase]);
        }
    };

    const int nt = K / 32;
    stage(0, 0);
    asm volatile("s_waitcnt vmcnt(0)" ::: "memory");
    __builtin_amdgcn_s_barrier();

    for (int kt = 0; kt < nt; kt++) {
        int cur = kt & 1;
        if (kt + 1 < nt) stage(cur ^ 1, kt + 1);     // issue-early (overlaps MFMA)
        bf16x8 af[MI], bfr[NI];
        #pragma unroll
        for (int mi = 0; mi < MI; mi++)
            af[mi] = *(const bf16x8*)&As[cur][(wm + mi * 16 + lr) * 32 + lg * 8];
        #pragma unroll
        for (int ni = 0; ni < NI; ni++)
            bfr[ni] = *(const bf16x8*)&Bs[cur][(wn + ni * 16 + lr) * 32 + lg * 8];
        __builtin_amdgcn_s_setprio(1);
        #pragma unroll
        for (int mi = 0; mi < MI; mi++)
            #pragma unroll
            for (int ni = 0; ni < NI; ni++)
                acc[mi][ni] = __builtin_amdgcn_mfma_f32_16x16x32_bf16(af[mi], bfr[ni], acc[mi][ni], 0, 0, 0);
        __builtin_amdgcn_s_setprio(0);
        asm volatile("s_waitcnt vmcnt(0)" ::: "memory");   // next tile landed
        __builtin_amdgcn_s_barrier();
    }

    #pragma unroll
    for (int mi = 0; mi < MI; mi++)
    #pragma unroll
    for (int ni = 0; ni < NI; ni++)
    #pragma unroll
    for (int r = 0; r < 4; r++) {
        long row = m0 + wm + mi * 16 + lg * 4 + r;
        long col = n0 + wn + ni * 16 + lr;
        float v = acc[mi][ni][r];
        if (WRITE_BF16) ((short*)Cv)[row * N + col] = f2bf(v);
        else            ((float*)Cv)[row * N + col] = v;
    }
}

// ------- fused epilogue of QKV: Q/K RMSNorm+RoPE + V transpose, one launch --
// bid < 8192: Q rows; < 10240: K rows; < 10752: V transpose tiles
__global__ __launch_bounds__(256) void qkv_post_kernel(
    const short* __restrict__ C, short* __restrict__ qout, short* __restrict__ kout,
    short* __restrict__ vr,
    const float* __restrict__ qw, const float* __restrict__ kw,
    const float* __restrict__ cosb, const float* __restrict__ sinb) {
    __shared__ short tile[64][65];
    int bid = blockIdx.x;
    int t = threadIdx.x;

    if (bid >= 10240) {                      // ---- V transpose ----
        int vbid = bid - 10240;              // 512 blocks = 32 x 4 x 4
        int s0 = (vbid & 31) * 64, d0 = ((vbid >> 5) & 3) * 64;
        int bkv = vbid >> 7; int b = bkv >> 1, kv = bkv & 1;
        #pragma unroll
        for (int i = 0; i < 16; i++) {
            int flat = i * 256 + t; int si = flat >> 6, di = flat & 63;
            tile[si][di] = C[(long)(b * S_LEN + s0 + si) * 3072 + 2560 + kv * 256 + d0 + di];
        }
        __syncthreads();
        #pragma unroll
        for (int i = 0; i < 16; i++) {
            int flat = i * 256 + t; int di = flat >> 6, si = flat & 63;
            vr[(long)(bkv * 256 + d0 + di) * S_LEN + s0 + si] = tile[si][di];
        }
        return;
    }

    bool isQ = bid < 8192;
    int H        = isQ ? 8 : 2;
    long cofs    = isQ ? 0L : 2048L;
    const float* w = isQ ? qw : kw;
    short* out   = isQ ? qout : kout;
    long ob      = isQ ? 4194304L : 1048576L;
    long oh      = isQ ? 256L : 524288L;
    long os      = isQ ? 2048L : 256L;
    float scale  = isQ ? 0.0625f : 1.0f;
    int vec = (isQ ? bid : bid - 8192) * 4 + (t >> 6);
    int lane = t & 63;
    int token = vec / H, head = vec % H;
    int b = token / S_LEN, s = token % S_LEN;

    bf16x4 xv = *(const bf16x4*)(C + (long)token * 3072 + cofs + head * 256 + lane * 4);
    float x0 = bf2f(xv[0]), x1 = bf2f(xv[1]), x2 = bf2f(xv[2]), x3 = bf2f(xv[3]);
    float ss = x0 * x0 + x1 * x1 + x2 * x2 + x3 * x3;
    #pragma unroll
    for (int m = 1; m < 64; m <<= 1) ss += __shfl_xor(ss, m);
    float inv = rsqrtf(ss * (1.f / 256.f) + 1e-6f);

    float4 wv = *(const float4*)(w + lane * 4);
    float y0 = x0 * inv * (1.f + wv.x);
    float y1 = x1 * inv * (1.f + wv.y);
    float y2 = x2 * inv * (1.f + wv.z);
    float y3 = x3 * inv * (1.f + wv.w);

    if (lane < 16) {
        float2 c = *(const float2*)&cosb[s * 32 + lane * 2];
        float2 sn = *(const float2*)&sinb[s * 32 + lane * 2];
        float a0 = y0 * c.x - y1 * sn.x, b0 = y0 * sn.x + y1 * c.x;
        float a1 = y2 * c.y - y3 * sn.y, b1 = y2 * sn.y + y3 * c.y;
        y0 = a0; y1 = b0; y2 = a1; y3 = b1;
    }
    y0 *= scale; y1 *= scale; y2 *= scale; y3 *= scale;
    long oidx = (long)b * ob + (long)head * oh + (long)s * os + lane * 4;
    bf16x4 o; o[0] = f2bf(y0); o[1] = f2bf(y1); o[2] = f2bf(y2); o[3] = f2bf(y3);
    *(bf16x4*)(out + oidx) = o;
}

// ---------------- flash attention: byte-exact r8/r15 (best measured) --------
// 4 waves (2 q-groups x 2 key parities), 64 q rows/block, 2 blocks/CU.
// Phase: vmcnt(0)|BAR|compute|BAR|stage(ph+1). Heavy-first XCD mapping.
__global__ __launch_bounds__(256, 2) void flash_kernel(const short* __restrict__ Q,
                                                       const short* __restrict__ Kt,
                                                       const short* __restrict__ Vt,
                                                       short* __restrict__ O) {
    // [0,32K): K tiles (parity p at p*16KB); [32K,64K): V tiles; epilogue reuses
    __shared__ __align__(16) char smem[66048];

    int idx = blockIdx.x;
    int xcd = idx & 7, slot = idx >> 3;      // consecutive blocks -> XCD round-robin
    int bh = xcd * 2 + (slot & 1);           // 2 bh per XCD -> 4MB KV in its L2
    int j  = 31 - (slot >> 1);               // chunk 0..31, heavy first
    int h = bh & 7, b = bh >> 3;
    int kv = h >> 2;
    int t = threadIdx.x, lane = t & 63, w = t >> 6;
    int g = w >> 1, p = w & 1;               // q-group, key parity
    int ln = lane & 31, hi = lane >> 5;
    int q0 = j * 64 + g * 32;
    int qg = q0 + ln;                        // this lane's q row (score column)

    const short* Kb = Kt + (long)(b * NKV + kv) * S_LEN * HD;
    const short* Vb = Vt + (long)(b * NKV + kv) * HD * S_LEN;

    // Q fragments in registers: Q[q=ln][dc*16 + hi*8 + e]
    bf16x8 qf[16];
    {
        const short* qrow = Q + ((long)(b * S_LEN + qg) * NHQ + h) * HD + hi * 8;
        #pragma unroll
        for (int dc = 0; dc < 16; dc++) qf[dc] = *(const bf16x8*)&qrow[dc * 16];
    }

    f32x16 acc[8];
    #pragma unroll
    for (int i = 0; i < 8; i++)
        #pragma unroll
        for (int jj = 0; jj < 16; jj++) acc[i][jj] = 0.f;
    float m = -1e30f, l = 0.f;

    // stage tiles {2*ph2, 2*ph2+1} into parity slots 0/1 (16 loads/thread)
    auto stage = [&](int ph2) {
        #pragma unroll
        for (int pp = 0; pp < 2; pp++) {
            int k0s = (2 * ph2 + pp) * KVB;
            short* Ktile = (short*)(smem + pp * 16384);
            short* Vtile = (short*)(smem + 32768 + pp * 16384);
            #pragma unroll
            for (int c = 0; c < 4; c++) {
                int o = c * 4096 + w * 1024 + lane * 16;   // byte offset in tile
                int key = o >> 9, db = o & 511;
                gload16(Kb + (long)(k0s + key) * HD + ((db ^ ((key & 7) << 4)) >> 1),
                        Ktile + (c * 4096 + w * 1024) / 2);
                int d = o >> 6, kb = o & 63;
                gload16(Vb + (long)d * S_LEN + k0s + ((kb ^ ((d & 6) << 3)) >> 1),
                        Vtile + (c * 4096 + w * 1024) / 2);
            }
        }
    };

    auto compute = [&](int k0) {
        const char* Ks = (const char*)smem + p * 16384;
        const char* Vs = (const char*)smem + 32768 + p * 16384;
        // ---- QK^T (swapped): s = K * Q, D[key][q]; 2 chains ----
        f32x16 sA, sB;
        #pragma unroll
        for (int r = 0; r < 16; r++) { sA[r] = 0.f; sB[r] = 0.f; }
        __builtin_amdgcn_s_setprio(1);
        #pragma unroll
        for (int dc = 0; dc < 16; dc += 2) {
            int kb0 = (dc * 32 + hi * 16) ^ ((ln & 7) << 4);
            int kb1 = ((dc + 1) * 32 + hi * 16) ^ ((ln & 7) << 4);
            bf16x8 kf0 = *(const bf16x8*)(Ks + ln * 512 + kb0);
            bf16x8 kf1 = *(const bf16x8*)(Ks + ln * 512 + kb1);
            sA = __builtin_amdgcn_mfma_f32_32x32x16_bf16(kf0, qf[dc],     sA, 0, 0, 0);
            sB = __builtin_amdgcn_mfma_f32_32x32x16_bf16(kf1, qf[dc + 1], sB, 0, 0, 0);
        }
        __builtin_amdgcn_s_setprio(0);
        f32x16 s;
        #pragma unroll
        for (int r = 0; r < 16; r++) s[r] = sA[r] + sB[r];

        // ---- mask + online softmax, fully in-register ----
        if (k0 + KVB - 1 > q0) {
            #pragma unroll
            for (int r = 0; r < 16; r++) {
                int key_g = k0 + (r & 3) + 8 * (r >> 2) + 4 * hi;
                if (key_g > qg) s[r] = -1e30f;
            }
        }
        float mt = s[0];
        #pragma unroll
        for (int r = 1; r < 16; r++) mt = fmaxf(mt, s[r]);
        mt = fmaxf(mt, __shfl_xor(mt, 32));
        float mn = m;
        if (!__all(mt <= m + 8.f)) {           // defer-max (T13)
            mn = fmaxf(m, mt);
            float f = __expf(m - mn);
            m = mn;
            float fr[16];
            #pragma unroll
            for (int r = 0; r < 16; r++)
                fr[r] = bperm((r & 3) + 8 * (r >> 2) + 4 * hi, f);
            #pragma unroll
            for (int i = 0; i < 8; i++)
                #pragma unroll
                for (int r = 0; r < 16; r++) acc[i][r] *= fr[r];
            l *= f;
        }
        float pr[16], ps = 0.f;
        #pragma unroll
        for (int r = 0; r < 16; r++) { pr[r] = __expf(s[r] - mn); ps += pr[r]; }
        ps += __shfl_xor(ps, 32);
        l += ps;

        // ---- P -> bf16 A-fragments via cvt_pk + permlane32_swap (T12) ----
        unsigned pw[8];
        #pragma unroll
        for (int kc = 0; kc < 2; kc++) {
            unsigned X = cvtpk(pr[kc * 8 + 0], pr[kc * 8 + 1]);
            unsigned Y = cvtpk(pr[kc * 8 + 4], pr[kc * 8 + 5]);
            unsigned Z = cvtpk(pr[kc * 8 + 2], pr[kc * 8 + 3]);
            unsigned W = cvtpk(pr[kc * 8 + 6], pr[kc * 8 + 7]);
            asm volatile("v_permlane32_swap_b32 %0, %1" : "+v"(X), "+v"(Y));
            asm volatile("v_permlane32_swap_b32 %0, %1" : "+v"(Z), "+v"(W));
            pw[kc * 4 + 0] = X; pw[kc * 4 + 1] = Z;
            pw[kc * 4 + 2] = Y; pw[kc * 4 + 3] = W;
        }
        u32x4 w0v = {pw[0], pw[1], pw[2], pw[3]};
        u32x4 w1v = {pw[4], pw[5], pw[6], pw[7]};
        bf16x8 pa0 = __builtin_bit_cast(bf16x8, w0v);
        bf16x8 pa1 = __builtin_bit_cast(bf16x8, w1v);

        // ---- PV: acc[db] += P * V, D[q][d], lane owns d column ----
        __builtin_amdgcn_s_setprio(1);
        #pragma unroll
        for (int db = 0; db < 8; db++) {
            int drow = db * 32 + ln;
            int sw = (drow & 6) << 3;
            bf16x8 vf0 = *(const bf16x8*)(Vs + drow * 64 + ((hi * 16) ^ sw));
            bf16x8 vf1 = *(const bf16x8*)(Vs + drow * 64 + ((32 + hi * 16) ^ sw));
            acc[db] = __builtin_amdgcn_mfma_f32_32x32x16_bf16(pa0, vf0, acc[db], 0, 0, 0);
            acc[db] = __builtin_amdgcn_mfma_f32_32x32x16_bf16(pa1, vf1, acc[db], 0, 0, 0);
        }
        __builtin_amdgcn_s_setprio(0);
    };

    stage(0);
    for (int ph = 0; ph <= j; ph++) {
        asm volatile("s_waitcnt vmcnt(0)" ::: "memory");
        __builtin_amdgcn_s_barrier();
        int k0 = (2 * ph + p) * KVB;
        if (k0 <= q0 + 31) compute(k0);      // skip only fully-masked diagonal tile
        __builtin_amdgcn_s_barrier();
        if (ph < j) stage(ph + 1);
        __builtin_amdgcn_sched_barrier(0);
    }

    // ---- parity merge epilogue (staging LDS is dead) ----
    float* accb = (float*)smem;                 // [g][128][64] f32
    float* mlb  = (float*)(smem + 65536);       // m: [0,64), l: [64,128)
    if (p == 1) {
        #pragma unroll
        for (int db = 0; db < 8; db++)
            #pragma unroll
            for (int r = 0; r < 16; r++)
                accb[g * 8192 + (db * 16 + r) * 64 + hi * 32 + ln] = acc[db][r];
        if (hi == 0) { mlb[g * 32 + ln] = m; mlb[64 + g * 32 + ln] = l; }
    }
    __syncthreads();
    if (p == 0) {
        float m1 = mlb[g * 32 + ln], l1 = mlb[64 + g * 32 + ln];
        float M  = fmaxf(m, m1);
        float f0 = __expf(m - M), f1 = __expf(m1 - M);
        float lt = l * f0 + l1 * f1;
        float w0 = f0 / lt, w1 = f1 / lt;
        float fr0[16], fr1[16];
        #pragma unroll
        for (int r = 0; r < 16; r++) {
            int crow = (r & 3) + 8 * (r >> 2) + 4 * hi;
            fr0[r] = bperm(crow, w0);
            fr1[r] = bperm(crow, w1);
        }
        #pragma unroll
        for (int db = 0; db < 8; db++)
            #pragma unroll
            for (int r = 0; r < 16; r++) {
                float a1 = accb[g * 8192 + (db * 16 + r) * 64 + hi * 32 + ln];
                int qrow = q0 + (r & 3) + 8 * (r >> 2) + 4 * hi;
                O[(long)(b * S_LEN + qrow) * 2048 + h * HD + db * 32 + ln] =
                    f2bf(acc[db][r] * fr0[r] + a1 * fr1[r]);
            }
    }
}

extern "C" void kernel_launch(void* const* d_in, const int* in_sizes, int n_in,
                              void* d_out, int out_size, void* d_ws, size_t ws_size,
                              hipStream_t stream) {
    const float* x    = (const float*)d_in[0];
    const float* cosb = (const float*)d_in[1];
    const float* sinb = (const float*)d_in[2];
    // d_in[3] = mask: equivalent to causal; computed analytically in-kernel
    const float* wq   = (const float*)d_in[4];
    const float* wk   = (const float*)d_in[5];
    const float* wv   = (const float*)d_in[6];
    const float* wo   = (const float*)d_in[7];
    const float* qnw  = (const float*)d_in[8];
    const float* knw  = (const float*)d_in[9];
    float* out = (float*)d_out;

    char* ws = (char*)d_ws;
    short* xb   = (short*)(ws + 0);          // 4096x512 bf16               [0, 4194304)
    short* wfus = (short*)(ws + 4194304);    // [3072][512] wq|wk|wv^T      [4194304, 7340032)
    short* wot  = (short*)(ws + 7340032);    // [512][2048] wo^T            [7340032, 9437184)
    short* C    = (short*)(ws + 9437184);    // 4096x3072 fused QKV out     [9437184, 34603008)
    short* ao   = (short*)(ws + 9437184);    // flash out aliases C (C dead by then)
    short* qro  = (short*)(ws + 34603008);   // 4096x2048 roped Q           [34603008, 51380224)
    short* kr   = (short*)(ws + 51380224);   // [b][kv][s][d] 4 MB          [51380224, 55574528)
    short* vr   = (short*)(ws + 55574528);   // [b][kv][d][s] 4 MB          [55574528, 59768832)

    cvt_kernel<<<2048, 256, 0, stream>>>(x, xb, 2097152);
    wt_all_kernel<<<640, 256, 0, stream>>>(wq, wk, wv, wo, wfus, wot);

    // fused QKV projection: C[4096][3072]
    gemm_bt<128, 128, 1><<<dim3(24, 32), 256, 0, stream>>>(xb, wfus, C, 4096, 3072, 512);

    // Q/K norm+rope + V transpose, one launch
    qkv_post_kernel<<<10752, 256, 0, stream>>>(C, qro, kr, vr, qnw, knw, cosb, sinb);

    flash_kernel<<<512, 256, 0, stream>>>(qro, kr, vr, ao);

    // out projection: BM=64 -> 512 blocks, 2/CU co-resident for 2-phase overlap
    gemm_bt<64, 64, 0><<<dim3(8, 64), 256, 0, stream>>>(ao, wot, out, 4096, 512, 2048);
}